// Round 9
// baseline (290.440 us; speedup 1.0000x reference)
//
#include <hip/hip_runtime.h>
#include <math.h>

#define N_NODES 100000
#define N_EDGES 1000000
#define HID 64
#define OUT_DIM 32
#define NUM_GRAPHS 512
#define CAP 48      // max in-degree; deg ~ Poisson(10), P(any overflow) ~ 1e-13
#define NBUCK 196   // R19: dst >> 9 -> buckets of 512 nodes (2x pass-B blocks,
                    // write confinement preserved: one block per bucket)
#define BSHIFT 9
#define BMASK 511
#define BCAP 6144   // bucket capacity; mean 5102, ~14 sigma margin
#define ACHUNK 4096

typedef __attribute__((ext_vector_type(4))) float f4v;
typedef __attribute__((ext_vector_type(4))) int i4v;
typedef __attribute__((ext_vector_type(8))) short s8v;  // 8 bf16 in 4 VGPRs
typedef __attribute__((ext_vector_type(4))) short s4vs; // 4 bf16 in 2 VGPRs

// fp32 -> bf16 (RNE) and back, as raw shorts
static __device__ inline short f2bf(float f) {
  unsigned u = __float_as_uint(f);
  unsigned r = (u + 0x7fffu + ((u >> 16) & 1u)) >> 16;
  return (short)r;
}
static __device__ inline float bf2f(short s) {
  return __uint_as_float(((unsigned)(unsigned short)s) << 16);
}

// ---------------------------------------------------------------------------
// CSR build pass A + prep fused (512 threads, int4 edge loads).
// Blocks [0,nEB) bucket edges; blocks [nEB,..) weight tables + starts.
// ---------------------------------------------------------------------------
#define PREP_T (16384 + NUM_GRAPHS + 1)

__global__ __launch_bounds__(512) void bucket_prep_kernel(
    const int* __restrict__ ei, int* __restrict__ bedge,
    int* __restrict__ bcnt, int n_edges,
    const float* __restrict__ W1a, const float* __restrict__ W2a,
    const float* __restrict__ W1b, const float* __restrict__ W2b,
    short* __restrict__ wtab, const int* __restrict__ batch,
    int* __restrict__ starts) {
  int nEB = (n_edges + ACHUNK - 1) / ACHUNK;  // 245 edge blocks
  int tid = threadIdx.x;

  if ((int)blockIdx.x >= nEB) {  // ----- prep region -----
    int t = ((int)blockIdx.x - nEB) * 512 + tid;
    if (t < 16384) {  // 4 x 64x64 weight hi/lo transpose
      int which = t >> 12;
      int r = t & 4095;
      const float* W = (which == 0) ? W1a : (which == 1) ? W2a : (which == 2) ? W1b : W2b;
      short* hiT = wtab + which * 8192;
      short* loT = hiT + 4096;
      int n = r & 63, k = r >> 6;
      float w = W[k * HID + n];
      short h = f2bf(w);
      hiT[n * HID + k] = h;
      loT[n * HID + k] = f2bf(w - bf2f(h));
    } else if (t < PREP_T) {  // starts[g] = lower_bound(batch,g)
      int g = t - 16384;
      int lo = 0, hi = N_NODES;
      while (lo < hi) {
        int mid = (lo + hi) >> 1;
        if (batch[mid] < g) lo = mid + 1; else hi = mid;
      }
      starts[g] = lo;
    }
    return;
  }

  // ----- bucket region -----
  __shared__ int s_pack[ACHUNK];
  __shared__ unsigned char s_b[ACHUNK];
  __shared__ int s_sorted[ACHUNK];
  __shared__ int s_hist[NBUCK];
  __shared__ int s_off[NBUCK];
  __shared__ int s_base[NBUCK];

  int e0 = blockIdx.x * ACHUNK;
  int n = n_edges - e0;
  if (n > ACHUNK) n = ACHUNK;  // always a multiple of 4 (1e6 % 4 == 0)

  for (int i = tid; i < NBUCK; i += 512) s_hist[i] = 0;
  __syncthreads();

  // vectorized: 4 src + 4 dst per thread-iter
  for (int i0 = tid * 4; i0 < n; i0 += 2048) {
    i4v vs = *(const i4v*)(ei + e0 + i0);
    i4v vd = *(const i4v*)(ei + n_edges + e0 + i0);
#pragma unroll
    for (int k = 0; k < 4; k++) {
      int src = vs[k];
      int dst = vd[k];
      int b = dst >> BSHIFT;
      s_pack[i0 + k] = src | ((dst & BMASK) << 17);  // src:17b | dstLocal:9b
      s_b[i0 + k] = (unsigned char)b;                // 196 < 256: fits uchar
      atomicAdd(&s_hist[b], 1);
    }
  }
  __syncthreads();

  // parallel inclusive scan (196 entries), then make exclusive
  if (tid < NBUCK) s_off[tid] = s_hist[tid];
  __syncthreads();
  for (int off = 1; off < NBUCK; off <<= 1) {
    int v = 0;
    if (tid < NBUCK && tid >= off) v = s_off[tid - off];
    __syncthreads();
    if (tid < NBUCK && tid >= off) s_off[tid] += v;
    __syncthreads();
  }
  if (tid < NBUCK) {
    int excl = s_off[tid] - s_hist[tid];
    s_off[tid] = excl;
    int c = s_hist[tid];  // reserve global space per bucket
    s_base[tid] = c > 0 ? atomicAdd(&bcnt[tid], c) : 0;
  }
  __syncthreads();

  for (int i = tid; i < n; i += 512) {  // LDS scatter (sort)
    int p = atomicAdd(&s_off[s_b[i]], 1);
    s_sorted[p] = s_pack[i];
  }
  __syncthreads();

  // flush contiguous runs: wave w owns buckets w, w+8, ... (cnt wave-uniform)
  int wv = tid >> 6;
  int lane = tid & 63;
  for (int b = wv; b < NBUCK; b += 8) {
    int cnt = s_hist[b];
    if (cnt == 0) continue;
    int start = s_off[b] - cnt;  // s_off[b] is now end offset
    int gbase = s_base[b];
    for (int i = lane; i < cnt; i += 64) {
      int idx = gbase + i;
      if (idx < BCAP) bedge[b * BCAP + idx] = s_sorted[start + i];
    }
  }
}

// ---------------------------------------------------------------------------
// CSR build pass B. ONE block per bucket (R13 write-confinement invariant:
// private csr/deg slices, zero cross-block lines -- the R12/R17 shared-slice
// splits both regressed). R19: 196 buckets -> 77% CU coverage (was 38%).
// 1024 threads; LDS atomics on ldeg[512]; deg written once, coalesced.
// ---------------------------------------------------------------------------
__global__ __launch_bounds__(1024) void csr_from_buckets_kernel(
    const int* __restrict__ bedge, const int* __restrict__ bcnt,
    int* __restrict__ deg, int* __restrict__ csr) {
  __shared__ int ldeg[512];
  int b = blockIdx.x;
  int tid = threadIdx.x;
  if (tid < 512) ldeg[tid] = 0;
  __syncthreads();

  int n = bcnt[b];
  if (n > BCAP) n = BCAP;
  const int* bb = bedge + b * BCAP;  // BCAP % 4 == 0 -> int4-aligned
  for (int i0 = tid * 4; i0 < n; i0 += 4096) {
    int e0, e1, e2, e3;
    int rem = n - i0;
    if (rem >= 4) {
      i4v v = *(const i4v*)(bb + i0);
      e0 = v.x; e1 = v.y; e2 = v.z; e3 = v.w;
    } else {
      e0 = bb[i0];
      e1 = (rem > 1) ? bb[i0 + 1] : 0;
      e2 = (rem > 2) ? bb[i0 + 2] : 0;
      e3 = 0;
    }
    {
      int local = e0 >> 17, src = e0 & 0x1FFFF;
      int slot = atomicAdd(&ldeg[local], 1);
      if (slot < CAP) csr[(((size_t)b << BSHIFT) | local) * CAP + slot] = src;
    }
    if (rem > 1) {
      int local = e1 >> 17, src = e1 & 0x1FFFF;
      int slot = atomicAdd(&ldeg[local], 1);
      if (slot < CAP) csr[(((size_t)b << BSHIFT) | local) * CAP + slot] = src;
    }
    if (rem > 2) {
      int local = e2 >> 17, src = e2 & 0x1FFFF;
      int slot = atomicAdd(&ldeg[local], 1);
      if (slot < CAP) csr[(((size_t)b << BSHIFT) | local) * CAP + slot] = src;
    }
    if (rem > 3) {
      int local = e3 >> 17, src = e3 & 0x1FFFF;
      int slot = atomicAdd(&ldeg[local], 1);
      if (slot < CAP) csr[(((size_t)b << BSHIFT) | local) * CAP + slot] = src;
    }
  }
  __syncthreads();

  if (tid < 512) {  // coalesced deg writeout (2 KB private slice)
    int node = (b << BSHIFT) + tid;
    if (node < N_NODES) deg[node] = ldeg[tid];
  }
}

// ---------------------------------------------------------------------------
// Gather: hbuf[i] = x[i] + sum_j x[j], emitted as bf16 hi/lo planes.
// R3-R8 verdict: pinned at ~3.4 TB/s L2-miss-level BW for random 256B rows
// across 6 structural variants -- structural floor. UNTOUCHED.
// SHFL DISCIPLINE: every __shfl full-wave under uniform control; only loads
// predicated. DO NOT fuse with the MLP (R11: occupancy collapse).
// ---------------------------------------------------------------------------
__global__ __launch_bounds__(256) void gather_kernel(
    const float* __restrict__ x, const int* __restrict__ deg,
    const int* __restrict__ csr, short* __restrict__ hbufHi,
    short* __restrict__ hbufLo, int n_nodes) {
  int lane = threadIdx.x & 63;
  int node = blockIdx.x * (blockDim.x >> 6) + (threadIdx.x >> 6);
  if (node >= n_nodes) return;  // node uniform per wave -> whole wave exits
  int g = lane >> 4;
  int sub = lane & 15;

  const f4v* x4 = (const f4v*)x;
  // issue all three independent loads back-to-back (self row first)
  f4v a0 = (g == 0) ? x4[(size_t)node * 16 + sub] : (f4v){0.f, 0.f, 0.f, 0.f};
  int idx = (lane < 16) ? csr[node * CAP + lane] : 0;
  int d = deg[node];
  if (d > CAP) d = CAP;

  f4v a1 = {0.f, 0.f, 0.f, 0.f};
  f4v a2 = {0.f, 0.f, 0.f, 0.f};
  f4v a3 = {0.f, 0.f, 0.f, 0.f};
  if (d > 0) {  // uniform; 16 neighbors in flight covers 97% of nodes
    int j1 = g, j2 = 4 + g, j3 = 8 + g, j4 = 12 + g;
    int s1 = __shfl(idx, j1);  // full-wave, unconditional
    int s2 = __shfl(idx, j2);
    int s3 = __shfl(idx, j3);
    int s4 = __shfl(idx, j4);
    if (j1 < d) a0 += x4[(size_t)s1 * 16 + sub];  // predicated load only
    if (j2 < d) a1 += x4[(size_t)s2 * 16 + sub];
    if (j3 < d) a2 += x4[(size_t)s3 * 16 + sub];
    if (j4 < d) a3 += x4[(size_t)s4 * 16 + sub];
  }
  if (d > 16) {  // uniform spill path, ~2.7% of waves
    int idx2 = (lane < 32) ? csr[node * CAP + 16 + lane] : 0;  // slots 16..47
    for (int j0 = 16; j0 < d; j0 += 16) {
      int j1 = j0 + g, j2 = j0 + 4 + g, j3 = j0 + 8 + g, j4 = j0 + 12 + g;
      int s1 = __shfl(idx2, j1 - 16);
      int s2 = __shfl(idx2, j2 - 16);
      int s3 = __shfl(idx2, j3 - 16);
      int s4 = __shfl(idx2, j4 - 16);
      if (j1 < d) a0 += x4[(size_t)s1 * 16 + sub];
      if (j2 < d) a1 += x4[(size_t)s2 * 16 + sub];
      if (j3 < d) a2 += x4[(size_t)s3 * 16 + sub];
      if (j4 < d) a3 += x4[(size_t)s4 * 16 + sub];
    }
  }
  f4v a = (a0 + a1) + (a2 + a3);
  a.x += __shfl_xor(a.x, 16); a.y += __shfl_xor(a.y, 16);
  a.z += __shfl_xor(a.z, 16); a.w += __shfl_xor(a.w, 16);
  a.x += __shfl_xor(a.x, 32); a.y += __shfl_xor(a.y, 32);
  a.z += __shfl_xor(a.z, 32); a.w += __shfl_xor(a.w, 32);
  if (g == 0) {
    s4vs hi, lo;
#pragma unroll
    for (int c = 0; c < 4; c++) {
      float v = a[c];
      short hb = f2bf(v);
      hi[c] = hb;
      lo[c] = f2bf(v - bf2f(hb));
    }
    ((s4vs*)hbufHi)[(size_t)node * 16 + sub] = hi;
    ((s4vs*)hbufLo)[(size_t)node * 16 + sub] = lo;
  }
}

// ---------------------------------------------------------------------------
// GIN MLP via MFMA (bf16 hi/lo split, fp32 accumulate; lo x lo dropped).
// R17-proven: 32 nodes per wave (two 16-row m-tiles), 8 MFMA chains,
// weights loaded once / used twice. 36 KB LDS -> 4 blocks (16 waves)/CU.
// ---------------------------------------------------------------------------
#define LPAD 72  // LDS row stride in shorts

__global__ __launch_bounds__(256) void gin_mlp_mfma_kernel(
    const short* __restrict__ hbufHi, const short* __restrict__ hbufLo,
    const short* __restrict__ W1hi, const short* __restrict__ W1lo,
    const float* __restrict__ b1,
    const short* __restrict__ W2hi, const short* __restrict__ W2lo,
    const float* __restrict__ b2,
    float* __restrict__ out, int n_nodes, int apply_relu) {
  __shared__ short lds[4][2][32 * LPAD];  // 36 KB/block: 4 blocks/CU

  int lane = threadIdx.x & 63;
  int wv = threadIdx.x >> 6;
  int m = lane & 15;
  int quad = lane >> 4;
  int nodeBase = blockIdx.x * 128 + wv * 32;  // 32 nodes per wave
  int node0 = nodeBase + m;
  int node1 = nodeBase + 16 + m;
  bool valid0 = node0 < n_nodes;
  bool valid1 = node1 < n_nodes;

  s8v ahi0[2], alo0[2], ahi1[2], alo1[2];
#pragma unroll
  for (int kb = 0; kb < 2; kb++) {
    int koff = kb * 32 + quad * 8;
    if (valid0) {
      ahi0[kb] = *(const s8v*)(hbufHi + node0 * HID + koff);
      alo0[kb] = *(const s8v*)(hbufLo + node0 * HID + koff);
    } else {
      ahi0[kb] = (s8v){0, 0, 0, 0, 0, 0, 0, 0};
      alo0[kb] = (s8v){0, 0, 0, 0, 0, 0, 0, 0};
    }
    if (valid1) {
      ahi1[kb] = *(const s8v*)(hbufHi + node1 * HID + koff);
      alo1[kb] = *(const s8v*)(hbufLo + node1 * HID + koff);
    } else {
      ahi1[kb] = (s8v){0, 0, 0, 0, 0, 0, 0, 0};
      alo1[kb] = (s8v){0, 0, 0, 0, 0, 0, 0, 0};
    }
  }

  f4v acc0[4], acc1[4];
#pragma unroll
  for (int nt = 0; nt < 4; nt++) {
    acc0[nt] = (f4v){0.f, 0.f, 0.f, 0.f};
    acc1[nt] = (f4v){0.f, 0.f, 0.f, 0.f};
  }
#pragma unroll
  for (int kb = 0; kb < 2; kb++) {
#pragma unroll
    for (int nt = 0; nt < 4; nt++) {
      int n = nt * 16 + m;
      s8v bh = *(const s8v*)(W1hi + n * HID + kb * 32 + quad * 8);
      s8v bl = *(const s8v*)(W1lo + n * HID + kb * 32 + quad * 8);
      acc0[nt] = __builtin_amdgcn_mfma_f32_16x16x32_bf16(ahi0[kb], bh, acc0[nt], 0, 0, 0);
      acc0[nt] = __builtin_amdgcn_mfma_f32_16x16x32_bf16(ahi0[kb], bl, acc0[nt], 0, 0, 0);
      acc0[nt] = __builtin_amdgcn_mfma_f32_16x16x32_bf16(alo0[kb], bh, acc0[nt], 0, 0, 0);
      acc1[nt] = __builtin_amdgcn_mfma_f32_16x16x32_bf16(ahi1[kb], bh, acc1[nt], 0, 0, 0);
      acc1[nt] = __builtin_amdgcn_mfma_f32_16x16x32_bf16(ahi1[kb], bl, acc1[nt], 0, 0, 0);
      acc1[nt] = __builtin_amdgcn_mfma_f32_16x16x32_bf16(alo1[kb], bh, acc1[nt], 0, 0, 0);
    }
  }

  short* Lhi = lds[wv][0];
  short* Llo = lds[wv][1];
#pragma unroll
  for (int nt = 0; nt < 4; nt++) {
    int col = nt * 16 + m;
    float bb = b1[col];
#pragma unroll
    for (int r = 0; r < 4; r++) {
      int row = quad * 4 + r;
      float h0 = fmaxf(acc0[nt][r] + bb, 0.f);
      short hb0 = f2bf(h0);
      Lhi[row * LPAD + col] = hb0;
      Llo[row * LPAD + col] = f2bf(h0 - bf2f(hb0));
      float h1 = fmaxf(acc1[nt][r] + bb, 0.f);
      short hb1 = f2bf(h1);
      Lhi[(16 + row) * LPAD + col] = hb1;
      Llo[(16 + row) * LPAD + col] = f2bf(h1 - bf2f(hb1));
    }
  }
  __syncthreads();

  s8v a2hi0[2], a2lo0[2], a2hi1[2], a2lo1[2];
#pragma unroll
  for (int kb = 0; kb < 2; kb++) {
    int koff = kb * 32 + quad * 8;
    a2hi0[kb] = *(const s8v*)(Lhi + m * LPAD + koff);
    a2lo0[kb] = *(const s8v*)(Llo + m * LPAD + koff);
    a2hi1[kb] = *(const s8v*)(Lhi + (16 + m) * LPAD + koff);
    a2lo1[kb] = *(const s8v*)(Llo + (16 + m) * LPAD + koff);
  }

  f4v acc20[4], acc21[4];
#pragma unroll
  for (int nt = 0; nt < 4; nt++) {
    acc20[nt] = (f4v){0.f, 0.f, 0.f, 0.f};
    acc21[nt] = (f4v){0.f, 0.f, 0.f, 0.f};
  }
#pragma unroll
  for (int kb = 0; kb < 2; kb++) {
#pragma unroll
    for (int nt = 0; nt < 4; nt++) {
      int n = nt * 16 + m;
      s8v bh = *(const s8v*)(W2hi + n * HID + kb * 32 + quad * 8);
      s8v bl = *(const s8v*)(W2lo + n * HID + kb * 32 + quad * 8);
      acc20[nt] = __builtin_amdgcn_mfma_f32_16x16x32_bf16(a2hi0[kb], bh, acc20[nt], 0, 0, 0);
      acc20[nt] = __builtin_amdgcn_mfma_f32_16x16x32_bf16(a2hi0[kb], bl, acc20[nt], 0, 0, 0);
      acc20[nt] = __builtin_amdgcn_mfma_f32_16x16x32_bf16(a2lo0[kb], bh, acc20[nt], 0, 0, 0);
      acc21[nt] = __builtin_amdgcn_mfma_f32_16x16x32_bf16(a2hi1[kb], bh, acc21[nt], 0, 0, 0);
      acc21[nt] = __builtin_amdgcn_mfma_f32_16x16x32_bf16(a2hi1[kb], bl, acc21[nt], 0, 0, 0);
      acc21[nt] = __builtin_amdgcn_mfma_f32_16x16x32_bf16(a2lo1[kb], bh, acc21[nt], 0, 0, 0);
    }
  }

#pragma unroll
  for (int nt = 0; nt < 4; nt++) {
    int col = nt * 16 + m;
    float bb = b2[col];
#pragma unroll
    for (int r = 0; r < 4; r++) {
      int row = quad * 4 + r;
      int onode0 = nodeBase + row;
      if (onode0 < n_nodes) {
        float o = acc20[nt][r] + bb;
        if (apply_relu) o = fmaxf(o, 0.f);
        out[(size_t)onode0 * HID + col] = o;
      }
      int onode1 = nodeBase + 16 + row;
      if (onode1 < n_nodes) {
        float o = acc21[nt][r] + bb;
        if (apply_relu) o = fmaxf(o, 0.f);
        out[(size_t)onode1 * HID + col] = o;
      }
    }
  }
}

// ---------------------------------------------------------------------------
// Fused pool + head (R18-proven): 4 waves per graph, 512 blocks x 256
// threads; partials combined via 768 B LDS; wave 0 runs the head.
// ---------------------------------------------------------------------------
__global__ __launch_bounds__(256) void poolhead_kernel(
    const float* __restrict__ emb, const int* __restrict__ starts,
    const float* __restrict__ Wp1, const float* __restrict__ bp1,
    const float* __restrict__ Wp2, const float* __restrict__ bp2,
    float* __restrict__ out) {
  __shared__ float part[3][64];
  int tid = threadIdx.x;
  int lane = tid & 63;
  int wv = tid >> 6;
  int g = blockIdx.x;  // one graph per block, 4 waves
  int group = lane >> 4, sub = lane & 15;
  int s0 = starts[g], s1 = starts[g + 1];

  const f4v* e4 = (const f4v*)emb;
  f4v acc = {0.f, 0.f, 0.f, 0.f};
  for (int n = s0 + wv * 4 + group; n < s1; n += 16) {
    f4v v = e4[(size_t)n * 16 + sub];
    v.x = fmaxf(v.x, 0.f); v.y = fmaxf(v.y, 0.f);
    v.z = fmaxf(v.z, 0.f); v.w = fmaxf(v.w, 0.f);
    acc += v;
  }
  acc.x += __shfl_xor(acc.x, 16); acc.y += __shfl_xor(acc.y, 16);
  acc.z += __shfl_xor(acc.z, 16); acc.w += __shfl_xor(acc.w, 16);
  acc.x += __shfl_xor(acc.x, 32); acc.y += __shfl_xor(acc.y, 32);
  acc.z += __shfl_xor(acc.z, 32); acc.w += __shfl_xor(acc.w, 32);
  // every lane l holds this wave's sums for dims [4*(l&15), 4*(l&15)+3].
  // redistribute: lane l wants dim l -> source lane l>>2, component l&3.
  int srcl = lane >> 2;
  float v0 = __shfl(acc.x, srcl);
  float v1 = __shfl(acc.y, srcl);
  float v2 = __shfl(acc.z, srcl);
  float v3 = __shfl(acc.w, srcl);
  int r = lane & 3;
  float p = (r == 0) ? v0 : (r == 1) ? v1 : (r == 2) ? v2 : v3;

  if (wv > 0) part[wv - 1][lane] = p;
  __syncthreads();
  if (wv != 0) return;  // wave-uniform exit

  p += (part[0][lane] + part[1][lane]) + part[2][lane];

  float c = fmaxf((float)(s1 - s0), 1.0f);
  p = p / c;

  float t = bp1[lane];
#pragma unroll
  for (int k = 0; k < HID; k++) {
    t += __shfl(p, k) * Wp1[k * HID + lane];
  }

  float acc2 = 0.0f;
#pragma unroll
  for (int k = 0; k < HID; k++) {
    float tk = __shfl(t, k);
    if (lane < OUT_DIM) acc2 += tk * Wp2[k * OUT_DIM + lane];
  }
  float o = (lane < OUT_DIM) ? (acc2 + bp2[lane]) : -1e30f;

  float m = o;
#pragma unroll
  for (int off = 32; off >= 1; off >>= 1) m = fmaxf(m, __shfl_xor(m, off));
  float ex = (lane < OUT_DIM) ? expf(o - m) : 0.0f;
  float s = ex;
#pragma unroll
  for (int off = 32; off >= 1; off >>= 1) s += __shfl_xor(s, off);
  float lse = m + logf(s);
  if (lane < OUT_DIM) out[g * OUT_DIM + lane] = o - lse;
}

extern "C" void kernel_launch(void* const* d_in, const int* in_sizes, int n_in,
                              void* d_out, int out_size, void* d_ws, size_t ws_size,
                              hipStream_t stream) {
  const float* x   = (const float*)d_in[0];
  const int* ei    = (const int*)d_in[1];
  const int* batch = (const int*)d_in[2];
  const float* W1a = (const float*)d_in[3];
  const float* b1a = (const float*)d_in[4];
  const float* W2a = (const float*)d_in[5];
  const float* b2a = (const float*)d_in[6];
  const float* W1b = (const float*)d_in[7];
  const float* b1b = (const float*)d_in[8];
  const float* W2b = (const float*)d_in[9];
  const float* b2b = (const float*)d_in[10];
  const float* Wp1 = (const float*)d_in[11];
  const float* bp1 = (const float*)d_in[12];
  const float* Wp2 = (const float*)d_in[13];
  const float* bp2 = (const float*)d_in[14];

  float* emb    = (float*)d_out;                          // [N_NODES, HID]
  float* logits = (float*)d_out + (size_t)N_NODES * HID;  // [NUM_GRAPHS, OUT_DIM]
  // x1 (relu'd layer-0 output) aliases emb: safe because gather and MLP are
  // SEPARATE dispatches (R9-proven). gather1 reads x1 -> hbuf; mlp1 reads
  // hbuf -> writes emb. No dispatch both reads and writes the region.
  float* x1 = emb;

  // ws: hbuf hi/lo planes [2 x N*HID bf16 = 25.6 MB; first ~4.9MB doubles as
  //     bedge+bcnt] | deg | csr | starts | wtab
  short* hbufHi = (short*)d_ws;                        // [N_NODES*HID] bf16 hi
  short* hbufLo = hbufHi + (size_t)N_NODES * HID;      // [N_NODES*HID] bf16 lo
  int* bedge   = (int*)d_ws;            // alias: dead before first gather
  int* bcnt    = bedge + NBUCK * BCAP;  // still inside hbuf region
  int* deg     = (int*)((float*)d_ws + (size_t)N_NODES * HID);
  int* csr     = deg + N_NODES;
  int* starts  = csr + (size_t)N_NODES * CAP;
  short* wtab  = (short*)(starts + NUM_GRAPHS + 1);
  short* W1aHi = wtab + 0 * 4096; short* W1aLo = wtab + 1 * 4096;
  short* W2aHi = wtab + 2 * 4096; short* W2aLo = wtab + 3 * 4096;
  short* W1bHi = wtab + 4 * 4096; short* W1bLo = wtab + 5 * 4096;
  short* W2bHi = wtab + 6 * 4096; short* W2bLo = wtab + 7 * 4096;

  // ----- zero bcnt (784 B) + fused bucket/prep (1 dispatch) -----
  hipMemsetAsync(bcnt, 0, NBUCK * sizeof(int), stream);
  int nEB = (N_EDGES + ACHUNK - 1) / ACHUNK;         // 245
  int prepB = (PREP_T + 511) / 512;                  // 33
  bucket_prep_kernel<<<nEB + prepB, 512, 0, stream>>>(
      ei, bedge, bcnt, N_EDGES, W1a, W2a, W1b, W2b, wtab, batch, starts);

  csr_from_buckets_kernel<<<NBUCK, 1024, 0, stream>>>(bedge, bcnt, deg, csr);

  int gather_blocks = (N_NODES + 3) / 4;   // 4 waves (nodes) per block
  int mlp_blocks = (N_NODES + 127) / 128;  // 128 nodes per block (32/wave)

  // ----- layer 0: hbuf = x + agg(x); x1 = relu(MLP_a(hbuf)) -----
  gather_kernel<<<gather_blocks, 256, 0, stream>>>(
      x, deg, csr, hbufHi, hbufLo, N_NODES);
  gin_mlp_mfma_kernel<<<mlp_blocks, 256, 0, stream>>>(
      hbufHi, hbufLo, W1aHi, W1aLo, b1a, W2aHi, W2aLo, b2a, x1, N_NODES, /*relu=*/1);

  // ----- layer 1: hbuf = x1 + agg(x1); emb = MLP_b(hbuf) (pre-ReLU) -----
  gather_kernel<<<gather_blocks, 256, 0, stream>>>(
      x1, deg, csr, hbufHi, hbufLo, N_NODES);
  gin_mlp_mfma_kernel<<<mlp_blocks, 256, 0, stream>>>(
      hbufHi, hbufLo, W1bHi, W1bLo, b1b, W2bHi, W2bLo, b2b, emb, N_NODES, /*relu=*/0);

  // ----- fused pooling + head (1 dispatch, 512 x 256, 4 waves/graph) -----
  poolhead_kernel<<<NUM_GRAPHS, 256, 0, stream>>>(
      emb, starts, Wp1, bp1, Wp2, bp2, logits);
}

// Round 10
// 284.711 us; speedup vs baseline: 1.0201x; 1.0201x over previous
//
#include <hip/hip_runtime.h>
#include <math.h>

#define N_NODES 100000
#define N_EDGES 1000000
#define HID 64
#define OUT_DIM 32
#define NUM_GRAPHS 512
#define CAP 48      // max in-degree; deg ~ Poisson(10), P(any overflow) ~ 1e-13
#define NBUCK 98    // R20: reverted to R8 (196-bucket variant was +3.6us)
#define BCAP 11264  // bucket capacity; mean 10204 -> 10+ sigma margin
#define ACHUNK 4096

typedef __attribute__((ext_vector_type(4))) float f4v;
typedef __attribute__((ext_vector_type(4))) int i4v;
typedef __attribute__((ext_vector_type(8))) short s8v;  // 8 bf16 in 4 VGPRs
typedef __attribute__((ext_vector_type(4))) short s4vs; // 4 bf16 in 2 VGPRs

// fp32 -> bf16 (RNE) and back, as raw shorts
static __device__ inline short f2bf(float f) {
  unsigned u = __float_as_uint(f);
  unsigned r = (u + 0x7fffu + ((u >> 16) & 1u)) >> 16;
  return (short)r;
}
static __device__ inline float bf2f(short s) {
  return __uint_as_float(((unsigned)(unsigned short)s) << 16);
}

// ---------------------------------------------------------------------------
// CSR build pass A + prep fused (512 threads, int4 edge loads).
// Blocks [0,nEB) bucket edges; blocks [nEB,..) weight tables + starts.
// ---------------------------------------------------------------------------
#define PREP_T (16384 + NUM_GRAPHS + 1)

__global__ __launch_bounds__(512) void bucket_prep_kernel(
    const int* __restrict__ ei, int* __restrict__ bedge,
    int* __restrict__ bcnt, int n_edges,
    const float* __restrict__ W1a, const float* __restrict__ W2a,
    const float* __restrict__ W1b, const float* __restrict__ W2b,
    short* __restrict__ wtab, const int* __restrict__ batch,
    int* __restrict__ starts) {
  int nEB = (n_edges + ACHUNK - 1) / ACHUNK;  // 245 edge blocks
  int tid = threadIdx.x;

  if ((int)blockIdx.x >= nEB) {  // ----- prep region -----
    int t = ((int)blockIdx.x - nEB) * 512 + tid;
    if (t < 16384) {  // 4 x 64x64 weight hi/lo transpose
      int which = t >> 12;
      int r = t & 4095;
      const float* W = (which == 0) ? W1a : (which == 1) ? W2a : (which == 2) ? W1b : W2b;
      short* hiT = wtab + which * 8192;
      short* loT = hiT + 4096;
      int n = r & 63, k = r >> 6;
      float w = W[k * HID + n];
      short h = f2bf(w);
      hiT[n * HID + k] = h;
      loT[n * HID + k] = f2bf(w - bf2f(h));
    } else if (t < PREP_T) {  // starts[g] = lower_bound(batch,g)
      int g = t - 16384;
      int lo = 0, hi = N_NODES;
      while (lo < hi) {
        int mid = (lo + hi) >> 1;
        if (batch[mid] < g) lo = mid + 1; else hi = mid;
      }
      starts[g] = lo;
    }
    return;
  }

  // ----- bucket region -----
  __shared__ int s_pack[ACHUNK];
  __shared__ unsigned char s_b[ACHUNK];
  __shared__ int s_sorted[ACHUNK];
  __shared__ int s_hist[NBUCK];
  __shared__ int s_off[NBUCK];
  __shared__ int s_base[NBUCK];

  int e0 = blockIdx.x * ACHUNK;
  int n = n_edges - e0;
  if (n > ACHUNK) n = ACHUNK;  // always a multiple of 4 (1e6 % 4 == 0)

  for (int i = tid; i < NBUCK; i += 512) s_hist[i] = 0;
  __syncthreads();

  // vectorized: 4 src + 4 dst per thread-iter
  for (int i0 = tid * 4; i0 < n; i0 += 2048) {
    i4v vs = *(const i4v*)(ei + e0 + i0);
    i4v vd = *(const i4v*)(ei + n_edges + e0 + i0);
#pragma unroll
    for (int k = 0; k < 4; k++) {
      int src = vs[k];
      int dst = vd[k];
      int b = dst >> 10;
      s_pack[i0 + k] = src | ((dst & 1023) << 17);  // src:17b | dstLocal:10b
      s_b[i0 + k] = (unsigned char)b;
      atomicAdd(&s_hist[b], 1);
    }
  }
  __syncthreads();

  // parallel inclusive scan (98 entries), then make exclusive
  if (tid < NBUCK) s_off[tid] = s_hist[tid];
  __syncthreads();
  for (int off = 1; off < NBUCK; off <<= 1) {
    int v = 0;
    if (tid < NBUCK && tid >= off) v = s_off[tid - off];
    __syncthreads();
    if (tid < NBUCK && tid >= off) s_off[tid] += v;
    __syncthreads();
  }
  if (tid < NBUCK) {
    int excl = s_off[tid] - s_hist[tid];
    s_off[tid] = excl;
    int c = s_hist[tid];  // reserve global space per bucket
    s_base[tid] = c > 0 ? atomicAdd(&bcnt[tid], c) : 0;
  }
  __syncthreads();

  for (int i = tid; i < n; i += 512) {  // LDS scatter (sort)
    int p = atomicAdd(&s_off[s_b[i]], 1);
    s_sorted[p] = s_pack[i];
  }
  __syncthreads();

  // flush contiguous runs: wave w owns buckets w, w+8, ... (cnt wave-uniform)
  int wv = tid >> 6;
  int lane = tid & 63;
  for (int b = wv; b < NBUCK; b += 8) {
    int cnt = s_hist[b];
    if (cnt == 0) continue;
    int start = s_off[b] - cnt;  // s_off[b] is now end offset
    int gbase = s_base[b];
    for (int i = lane; i < cnt; i += 64) {
      int idx = gbase + i;
      if (idx < BCAP) bedge[b * BCAP + idx] = s_sorted[start + i];
    }
  }
}

// ---------------------------------------------------------------------------
// CSR build pass B (R8-proven form, restored -- best measured config).
// ONE block per bucket (R13 write-confinement invariant: private csr/deg
// slices; R12/R17/R19 parallelism variants all regressed). 1024 threads;
// LDS atomics on ldeg[1024]; deg written once, coalesced.
// ---------------------------------------------------------------------------
__global__ __launch_bounds__(1024) void csr_from_buckets_kernel(
    const int* __restrict__ bedge, const int* __restrict__ bcnt,
    int* __restrict__ deg, int* __restrict__ csr) {
  __shared__ int ldeg[1024];
  int b = blockIdx.x;
  int tid = threadIdx.x;
  ldeg[tid] = 0;
  __syncthreads();

  int n = bcnt[b];
  if (n > BCAP) n = BCAP;
  const int* bb = bedge + b * BCAP;  // BCAP % 4 == 0 -> int4-aligned
  for (int i0 = tid * 4; i0 < n; i0 += 4096) {
    int e0, e1, e2, e3;
    int rem = n - i0;
    if (rem >= 4) {
      i4v v = *(const i4v*)(bb + i0);
      e0 = v.x; e1 = v.y; e2 = v.z; e3 = v.w;
    } else {
      e0 = bb[i0];
      e1 = (rem > 1) ? bb[i0 + 1] : 0;
      e2 = (rem > 2) ? bb[i0 + 2] : 0;
      e3 = 0;
    }
    {
      int local = e0 >> 17, src = e0 & 0x1FFFF;
      int slot = atomicAdd(&ldeg[local], 1);
      if (slot < CAP) csr[(((size_t)b << 10) | local) * CAP + slot] = src;
    }
    if (rem > 1) {
      int local = e1 >> 17, src = e1 & 0x1FFFF;
      int slot = atomicAdd(&ldeg[local], 1);
      if (slot < CAP) csr[(((size_t)b << 10) | local) * CAP + slot] = src;
    }
    if (rem > 2) {
      int local = e2 >> 17, src = e2 & 0x1FFFF;
      int slot = atomicAdd(&ldeg[local], 1);
      if (slot < CAP) csr[(((size_t)b << 10) | local) * CAP + slot] = src;
    }
    if (rem > 3) {
      int local = e3 >> 17, src = e3 & 0x1FFFF;
      int slot = atomicAdd(&ldeg[local], 1);
      if (slot < CAP) csr[(((size_t)b << 10) | local) * CAP + slot] = src;
    }
  }
  __syncthreads();

  int node = (b << 10) + tid;  // coalesced deg writeout
  if (node < N_NODES) deg[node] = ldeg[tid];
}

// ---------------------------------------------------------------------------
// Gather: hbuf[i] = x[i] + sum_j x[j], emitted as bf16 hi/lo planes.
// R3-R9 verdict: pinned at ~3.4 TB/s L2-miss-level BW for random 256B rows
// across 6 structural variants -- structural floor. UNTOUCHED.
// SHFL DISCIPLINE: every __shfl full-wave under uniform control; only loads
// predicated. DO NOT fuse with the MLP (R11: occupancy collapse).
// ---------------------------------------------------------------------------
__global__ __launch_bounds__(256) void gather_kernel(
    const float* __restrict__ x, const int* __restrict__ deg,
    const int* __restrict__ csr, short* __restrict__ hbufHi,
    short* __restrict__ hbufLo, int n_nodes) {
  int lane = threadIdx.x & 63;
  int node = blockIdx.x * (blockDim.x >> 6) + (threadIdx.x >> 6);
  if (node >= n_nodes) return;  // node uniform per wave -> whole wave exits
  int g = lane >> 4;
  int sub = lane & 15;

  const f4v* x4 = (const f4v*)x;
  // issue all three independent loads back-to-back (self row first)
  f4v a0 = (g == 0) ? x4[(size_t)node * 16 + sub] : (f4v){0.f, 0.f, 0.f, 0.f};
  int idx = (lane < 16) ? csr[node * CAP + lane] : 0;
  int d = deg[node];
  if (d > CAP) d = CAP;

  f4v a1 = {0.f, 0.f, 0.f, 0.f};
  f4v a2 = {0.f, 0.f, 0.f, 0.f};
  f4v a3 = {0.f, 0.f, 0.f, 0.f};
  if (d > 0) {  // uniform; 16 neighbors in flight covers 97% of nodes
    int j1 = g, j2 = 4 + g, j3 = 8 + g, j4 = 12 + g;
    int s1 = __shfl(idx, j1);  // full-wave, unconditional
    int s2 = __shfl(idx, j2);
    int s3 = __shfl(idx, j3);
    int s4 = __shfl(idx, j4);
    if (j1 < d) a0 += x4[(size_t)s1 * 16 + sub];  // predicated load only
    if (j2 < d) a1 += x4[(size_t)s2 * 16 + sub];
    if (j3 < d) a2 += x4[(size_t)s3 * 16 + sub];
    if (j4 < d) a3 += x4[(size_t)s4 * 16 + sub];
  }
  if (d > 16) {  // uniform spill path, ~2.7% of waves
    int idx2 = (lane < 32) ? csr[node * CAP + 16 + lane] : 0;  // slots 16..47
    for (int j0 = 16; j0 < d; j0 += 16) {
      int j1 = j0 + g, j2 = j0 + 4 + g, j3 = j0 + 8 + g, j4 = j0 + 12 + g;
      int s1 = __shfl(idx2, j1 - 16);
      int s2 = __shfl(idx2, j2 - 16);
      int s3 = __shfl(idx2, j3 - 16);
      int s4 = __shfl(idx2, j4 - 16);
      if (j1 < d) a0 += x4[(size_t)s1 * 16 + sub];
      if (j2 < d) a1 += x4[(size_t)s2 * 16 + sub];
      if (j3 < d) a2 += x4[(size_t)s3 * 16 + sub];
      if (j4 < d) a3 += x4[(size_t)s4 * 16 + sub];
    }
  }
  f4v a = (a0 + a1) + (a2 + a3);
  a.x += __shfl_xor(a.x, 16); a.y += __shfl_xor(a.y, 16);
  a.z += __shfl_xor(a.z, 16); a.w += __shfl_xor(a.w, 16);
  a.x += __shfl_xor(a.x, 32); a.y += __shfl_xor(a.y, 32);
  a.z += __shfl_xor(a.z, 32); a.w += __shfl_xor(a.w, 32);
  if (g == 0) {
    s4vs hi, lo;
#pragma unroll
    for (int c = 0; c < 4; c++) {
      float v = a[c];
      short hb = f2bf(v);
      hi[c] = hb;
      lo[c] = f2bf(v - bf2f(hb));
    }
    ((s4vs*)hbufHi)[(size_t)node * 16 + sub] = hi;
    ((s4vs*)hbufLo)[(size_t)node * 16 + sub] = lo;
  }
}

// ---------------------------------------------------------------------------
// GIN MLP via MFMA (bf16 hi/lo split, fp32 accumulate; lo x lo dropped).
// R17-proven: 32 nodes per wave (two 16-row m-tiles), 8 MFMA chains,
// weights loaded once / used twice. 36 KB LDS -> 4 blocks (16 waves)/CU.
// R20: mid-kernel __syncthreads REMOVED -- the LDS transpose buffer lds[wv]
// is strictly per-wave (each wave writes then reads only its own slice), so
// same-wave program order + compiler lgkmcnt waits suffice; the barrier only
// serialized stage-2 entry behind the slowest wave's stage-1.
// ---------------------------------------------------------------------------
#define LPAD 72  // LDS row stride in shorts

__global__ __launch_bounds__(256) void gin_mlp_mfma_kernel(
    const short* __restrict__ hbufHi, const short* __restrict__ hbufLo,
    const short* __restrict__ W1hi, const short* __restrict__ W1lo,
    const float* __restrict__ b1,
    const short* __restrict__ W2hi, const short* __restrict__ W2lo,
    const float* __restrict__ b2,
    float* __restrict__ out, int n_nodes, int apply_relu) {
  __shared__ short lds[4][2][32 * LPAD];  // 36 KB/block: 4 blocks/CU

  int lane = threadIdx.x & 63;
  int wv = threadIdx.x >> 6;
  int m = lane & 15;
  int quad = lane >> 4;
  int nodeBase = blockIdx.x * 128 + wv * 32;  // 32 nodes per wave
  int node0 = nodeBase + m;
  int node1 = nodeBase + 16 + m;
  bool valid0 = node0 < n_nodes;
  bool valid1 = node1 < n_nodes;

  s8v ahi0[2], alo0[2], ahi1[2], alo1[2];
#pragma unroll
  for (int kb = 0; kb < 2; kb++) {
    int koff = kb * 32 + quad * 8;
    if (valid0) {
      ahi0[kb] = *(const s8v*)(hbufHi + node0 * HID + koff);
      alo0[kb] = *(const s8v*)(hbufLo + node0 * HID + koff);
    } else {
      ahi0[kb] = (s8v){0, 0, 0, 0, 0, 0, 0, 0};
      alo0[kb] = (s8v){0, 0, 0, 0, 0, 0, 0, 0};
    }
    if (valid1) {
      ahi1[kb] = *(const s8v*)(hbufHi + node1 * HID + koff);
      alo1[kb] = *(const s8v*)(hbufLo + node1 * HID + koff);
    } else {
      ahi1[kb] = (s8v){0, 0, 0, 0, 0, 0, 0, 0};
      alo1[kb] = (s8v){0, 0, 0, 0, 0, 0, 0, 0};
    }
  }

  f4v acc0[4], acc1[4];
#pragma unroll
  for (int nt = 0; nt < 4; nt++) {
    acc0[nt] = (f4v){0.f, 0.f, 0.f, 0.f};
    acc1[nt] = (f4v){0.f, 0.f, 0.f, 0.f};
  }
#pragma unroll
  for (int kb = 0; kb < 2; kb++) {
#pragma unroll
    for (int nt = 0; nt < 4; nt++) {
      int n = nt * 16 + m;
      s8v bh = *(const s8v*)(W1hi + n * HID + kb * 32 + quad * 8);
      s8v bl = *(const s8v*)(W1lo + n * HID + kb * 32 + quad * 8);
      acc0[nt] = __builtin_amdgcn_mfma_f32_16x16x32_bf16(ahi0[kb], bh, acc0[nt], 0, 0, 0);
      acc0[nt] = __builtin_amdgcn_mfma_f32_16x16x32_bf16(ahi0[kb], bl, acc0[nt], 0, 0, 0);
      acc0[nt] = __builtin_amdgcn_mfma_f32_16x16x32_bf16(alo0[kb], bh, acc0[nt], 0, 0, 0);
      acc1[nt] = __builtin_amdgcn_mfma_f32_16x16x32_bf16(ahi1[kb], bh, acc1[nt], 0, 0, 0);
      acc1[nt] = __builtin_amdgcn_mfma_f32_16x16x32_bf16(ahi1[kb], bl, acc1[nt], 0, 0, 0);
      acc1[nt] = __builtin_amdgcn_mfma_f32_16x16x32_bf16(alo1[kb], bh, acc1[nt], 0, 0, 0);
    }
  }

  short* Lhi = lds[wv][0];
  short* Llo = lds[wv][1];
#pragma unroll
  for (int nt = 0; nt < 4; nt++) {
    int col = nt * 16 + m;
    float bb = b1[col];
#pragma unroll
    for (int r = 0; r < 4; r++) {
      int row = quad * 4 + r;
      float h0 = fmaxf(acc0[nt][r] + bb, 0.f);
      short hb0 = f2bf(h0);
      Lhi[row * LPAD + col] = hb0;
      Llo[row * LPAD + col] = f2bf(h0 - bf2f(hb0));
      float h1 = fmaxf(acc1[nt][r] + bb, 0.f);
      short hb1 = f2bf(h1);
      Lhi[(16 + row) * LPAD + col] = hb1;
      Llo[(16 + row) * LPAD + col] = f2bf(h1 - bf2f(hb1));
    }
  }
  // NO __syncthreads(): lds[wv] is wave-private; same-wave write->read is
  // ordered by program order + compiler-inserted lgkmcnt waits.

  s8v a2hi0[2], a2lo0[2], a2hi1[2], a2lo1[2];
#pragma unroll
  for (int kb = 0; kb < 2; kb++) {
    int koff = kb * 32 + quad * 8;
    a2hi0[kb] = *(const s8v*)(Lhi + m * LPAD + koff);
    a2lo0[kb] = *(const s8v*)(Llo + m * LPAD + koff);
    a2hi1[kb] = *(const s8v*)(Lhi + (16 + m) * LPAD + koff);
    a2lo1[kb] = *(const s8v*)(Llo + (16 + m) * LPAD + koff);
  }

  f4v acc20[4], acc21[4];
#pragma unroll
  for (int nt = 0; nt < 4; nt++) {
    acc20[nt] = (f4v){0.f, 0.f, 0.f, 0.f};
    acc21[nt] = (f4v){0.f, 0.f, 0.f, 0.f};
  }
#pragma unroll
  for (int kb = 0; kb < 2; kb++) {
#pragma unroll
    for (int nt = 0; nt < 4; nt++) {
      int n = nt * 16 + m;
      s8v bh = *(const s8v*)(W2hi + n * HID + kb * 32 + quad * 8);
      s8v bl = *(const s8v*)(W2lo + n * HID + kb * 32 + quad * 8);
      acc20[nt] = __builtin_amdgcn_mfma_f32_16x16x32_bf16(a2hi0[kb], bh, acc20[nt], 0, 0, 0);
      acc20[nt] = __builtin_amdgcn_mfma_f32_16x16x32_bf16(a2hi0[kb], bl, acc20[nt], 0, 0, 0);
      acc20[nt] = __builtin_amdgcn_mfma_f32_16x16x32_bf16(a2lo0[kb], bh, acc20[nt], 0, 0, 0);
      acc21[nt] = __builtin_amdgcn_mfma_f32_16x16x32_bf16(a2hi1[kb], bh, acc21[nt], 0, 0, 0);
      acc21[nt] = __builtin_amdgcn_mfma_f32_16x16x32_bf16(a2hi1[kb], bl, acc21[nt], 0, 0, 0);
      acc21[nt] = __builtin_amdgcn_mfma_f32_16x16x32_bf16(a2lo1[kb], bh, acc21[nt], 0, 0, 0);
    }
  }

#pragma unroll
  for (int nt = 0; nt < 4; nt++) {
    int col = nt * 16 + m;
    float bb = b2[col];
#pragma unroll
    for (int r = 0; r < 4; r++) {
      int row = quad * 4 + r;
      int onode0 = nodeBase + row;
      if (onode0 < n_nodes) {
        float o = acc20[nt][r] + bb;
        if (apply_relu) o = fmaxf(o, 0.f);
        out[(size_t)onode0 * HID + col] = o;
      }
      int onode1 = nodeBase + 16 + row;
      if (onode1 < n_nodes) {
        float o = acc21[nt][r] + bb;
        if (apply_relu) o = fmaxf(o, 0.f);
        out[(size_t)onode1 * HID + col] = o;
      }
    }
  }
}

// ---------------------------------------------------------------------------
// Fused pool + head (R18-proven): 4 waves per graph, 512 blocks x 256
// threads; partials combined via 768 B LDS; wave 0 runs the head.
// ---------------------------------------------------------------------------
__global__ __launch_bounds__(256) void poolhead_kernel(
    const float* __restrict__ emb, const int* __restrict__ starts,
    const float* __restrict__ Wp1, const float* __restrict__ bp1,
    const float* __restrict__ Wp2, const float* __restrict__ bp2,
    float* __restrict__ out) {
  __shared__ float part[3][64];
  int tid = threadIdx.x;
  int lane = tid & 63;
  int wv = tid >> 6;
  int g = blockIdx.x;  // one graph per block, 4 waves
  int group = lane >> 4, sub = lane & 15;
  int s0 = starts[g], s1 = starts[g + 1];

  const f4v* e4 = (const f4v*)emb;
  f4v acc = {0.f, 0.f, 0.f, 0.f};
  for (int n = s0 + wv * 4 + group; n < s1; n += 16) {
    f4v v = e4[(size_t)n * 16 + sub];
    v.x = fmaxf(v.x, 0.f); v.y = fmaxf(v.y, 0.f);
    v.z = fmaxf(v.z, 0.f); v.w = fmaxf(v.w, 0.f);
    acc += v;
  }
  acc.x += __shfl_xor(acc.x, 16); acc.y += __shfl_xor(acc.y, 16);
  acc.z += __shfl_xor(acc.z, 16); acc.w += __shfl_xor(acc.w, 16);
  acc.x += __shfl_xor(acc.x, 32); acc.y += __shfl_xor(acc.y, 32);
  acc.z += __shfl_xor(acc.z, 32); acc.w += __shfl_xor(acc.w, 32);
  // every lane l holds this wave's sums for dims [4*(l&15), 4*(l&15)+3].
  // redistribute: lane l wants dim l -> source lane l>>2, component l&3.
  int srcl = lane >> 2;
  float v0 = __shfl(acc.x, srcl);
  float v1 = __shfl(acc.y, srcl);
  float v2 = __shfl(acc.z, srcl);
  float v3 = __shfl(acc.w, srcl);
  int r = lane & 3;
  float p = (r == 0) ? v0 : (r == 1) ? v1 : (r == 2) ? v2 : v3;

  if (wv > 0) part[wv - 1][lane] = p;
  __syncthreads();
  if (wv != 0) return;  // wave-uniform exit

  p += (part[0][lane] + part[1][lane]) + part[2][lane];

  float c = fmaxf((float)(s1 - s0), 1.0f);
  p = p / c;

  float t = bp1[lane];
#pragma unroll
  for (int k = 0; k < HID; k++) {
    t += __shfl(p, k) * Wp1[k * HID + lane];
  }

  float acc2 = 0.0f;
#pragma unroll
  for (int k = 0; k < HID; k++) {
    float tk = __shfl(t, k);
    if (lane < OUT_DIM) acc2 += tk * Wp2[k * OUT_DIM + lane];
  }
  float o = (lane < OUT_DIM) ? (acc2 + bp2[lane]) : -1e30f;

  float m = o;
#pragma unroll
  for (int off = 32; off >= 1; off >>= 1) m = fmaxf(m, __shfl_xor(m, off));
  float ex = (lane < OUT_DIM) ? expf(o - m) : 0.0f;
  float s = ex;
#pragma unroll
  for (int off = 32; off >= 1; off >>= 1) s += __shfl_xor(s, off);
  float lse = m + logf(s);
  if (lane < OUT_DIM) out[g * OUT_DIM + lane] = o - lse;
}

extern "C" void kernel_launch(void* const* d_in, const int* in_sizes, int n_in,
                              void* d_out, int out_size, void* d_ws, size_t ws_size,
                              hipStream_t stream) {
  const float* x   = (const float*)d_in[0];
  const int* ei    = (const int*)d_in[1];
  const int* batch = (const int*)d_in[2];
  const float* W1a = (const float*)d_in[3];
  const float* b1a = (const float*)d_in[4];
  const float* W2a = (const float*)d_in[5];
  const float* b2a = (const float*)d_in[6];
  const float* W1b = (const float*)d_in[7];
  const float* b1b = (const float*)d_in[8];
  const float* W2b = (const float*)d_in[9];
  const float* b2b = (const float*)d_in[10];
  const float* Wp1 = (const float*)d_in[11];
  const float* bp1 = (const float*)d_in[12];
  const float* Wp2 = (const float*)d_in[13];
  const float* bp2 = (const float*)d_in[14];

  float* emb    = (float*)d_out;                          // [N_NODES, HID]
  float* logits = (float*)d_out + (size_t)N_NODES * HID;  // [NUM_GRAPHS, OUT_DIM]
  // x1 (relu'd layer-0 output) aliases emb: safe because gather and MLP are
  // SEPARATE dispatches (R9-proven). gather1 reads x1 -> hbuf; mlp1 reads
  // hbuf -> writes emb. No dispatch both reads and writes the region.
  float* x1 = emb;

  // ws: hbuf hi/lo planes [2 x N*HID bf16 = 25.6 MB; first 4.4MB doubles as
  //     bedge+bcnt] | deg | csr | starts | wtab
  short* hbufHi = (short*)d_ws;                        // [N_NODES*HID] bf16 hi
  short* hbufLo = hbufHi + (size_t)N_NODES * HID;      // [N_NODES*HID] bf16 lo
  int* bedge   = (int*)d_ws;            // alias: dead before first gather
  int* bcnt    = bedge + NBUCK * BCAP;  // still inside hbuf region
  int* deg     = (int*)((float*)d_ws + (size_t)N_NODES * HID);
  int* csr     = deg + N_NODES;
  int* starts  = csr + (size_t)N_NODES * CAP;
  short* wtab  = (short*)(starts + NUM_GRAPHS + 1);
  short* W1aHi = wtab + 0 * 4096; short* W1aLo = wtab + 1 * 4096;
  short* W2aHi = wtab + 2 * 4096; short* W2aLo = wtab + 3 * 4096;
  short* W1bHi = wtab + 4 * 4096; short* W1bLo = wtab + 5 * 4096;
  short* W2bHi = wtab + 6 * 4096; short* W2bLo = wtab + 7 * 4096;

  // ----- zero bcnt (392 B) + fused bucket/prep (1 dispatch) -----
  hipMemsetAsync(bcnt, 0, NBUCK * sizeof(int), stream);
  int nEB = (N_EDGES + ACHUNK - 1) / ACHUNK;         // 245
  int prepB = (PREP_T + 511) / 512;                  // 33
  bucket_prep_kernel<<<nEB + prepB, 512, 0, stream>>>(
      ei, bedge, bcnt, N_EDGES, W1a, W2a, W1b, W2b, wtab, batch, starts);

  csr_from_buckets_kernel<<<NBUCK, 1024, 0, stream>>>(bedge, bcnt, deg, csr);

  int gather_blocks = (N_NODES + 3) / 4;   // 4 waves (nodes) per block
  int mlp_blocks = (N_NODES + 127) / 128;  // 128 nodes per block (32/wave)

  // ----- layer 0: hbuf = x + agg(x); x1 = relu(MLP_a(hbuf)) -----
  gather_kernel<<<gather_blocks, 256, 0, stream>>>(
      x, deg, csr, hbufHi, hbufLo, N_NODES);
  gin_mlp_mfma_kernel<<<mlp_blocks, 256, 0, stream>>>(
      hbufHi, hbufLo, W1aHi, W1aLo, b1a, W2aHi, W2aLo, b2a, x1, N_NODES, /*relu=*/1);

  // ----- layer 1: hbuf = x1 + agg(x1); emb = MLP_b(hbuf) (pre-ReLU) -----
  gather_kernel<<<gather_blocks, 256, 0, stream>>>(
      x1, deg, csr, hbufHi, hbufLo, N_NODES);
  gin_mlp_mfma_kernel<<<mlp_blocks, 256, 0, stream>>>(
      hbufHi, hbufLo, W1bHi, W1bLo, b1b, W2bHi, W2bLo, b2b, emb, N_NODES, /*relu=*/0);

  // ----- fused pooling + head (1 dispatch, 512 x 256, 4 waves/graph) -----
  poolhead_kernel<<<NUM_GRAPHS, 256, 0, stream>>>(
      emb, starts, Wp1, bp1, Wp2, bp2, logits);
}